// Round 6
// baseline (112.102 us; speedup 1.0000x reference)
//
#include <hip/hip_runtime.h>

#define IMG_H 1024
#define IMG_W 1024
#define TILES 16                 // 16x16 output tiles per block (32x32 px)
#define NPJ 17                   // patches per dim incl. halo
#define NPATCH (NPJ * NPJ)       // 289
#define PSTRH 20                 // __fp16 units per patch record (40 B: 16 used + pad)

typedef __attribute__((ext_vector_type(2))) __fp16 h2;

static __device__ __forceinline__ float h2_as_f(h2 v) {
    union { h2 h; float f; } u; u.h = v; return u.f;
}
static __device__ __forceinline__ h2 f_as_h2(float f) {
    union { float f; h2 h; } u; u.f = f; return u.h;
}

__global__ __launch_bounds__(256) void ae_fused(
    const float* __restrict__ img,
    const float* __restrict__ w_conv,
    const float* __restrict__ b_conv,
    const float* __restrict__ W_b,
    const float* __restrict__ b_b,
    const float* __restrict__ W_d,
    const float* __restrict__ b_d,
    float* __restrict__ out)
{
    __shared__ __align__(16) __fp16 dec[NPATCH * PSTRH];   // 11560 B -> 8 blocks/CU

    const int t  = threadIdx.x;
    const int n0 = blockIdx.x * TILES;
    const int m0 = blockIdx.y * TILES;
    const int b  = blockIdx.z;

    // uniform weights; decoder weights pre-negated and pre-scaled by log2(e)
    const float LOG2E = 1.4426950408889634f;
    float wc[2][4], nwd[2][4], wb[2][2];
    #pragma unroll
    for (int c = 0; c < 2; ++c) {
        #pragma unroll
        for (int q = 0; q < 4; ++q) {
            wc[c][q]  = w_conv[c * 4 + q];
            nwd[c][q] = -W_d[c * 4 + q] * LOG2E;
        }
    }
    wb[0][0] = W_b[0]; wb[0][1] = W_b[1];
    wb[1][0] = W_b[2]; wb[1][1] = W_b[3];
    const float bc0 = b_conv[0], bc1 = b_conv[1];
    const float bb0 = b_b[0],   bb1 = b_b[1];
    const float nbd = -b_d[0] * LOG2E;
    const float scf = 1.0f / (1.0f + exp2f(nbd));            // sigmoid(b_d)
    const h2 ch = { (__fp16)scf, (__fp16)scf };
    const h2 zh = { (__fp16)0.0f, (__fp16)0.0f };

    const float* imgb = img + (size_t)b * IMG_H * IMG_W;

    // ---- stage 1: one thread per patch: conv+argmax+bottleneck+decode+sigmoid -> f16 LDS ----
    #pragma unroll
    for (int it = 0; it < 2; ++it) {
        const int lp = t + it * 256;
        if (lp < NPATCH) {
            const int lpj = lp / NPJ;
            const int lpk = lp - lpj * NPJ;
            const int j = m0 - 1 + lpj;
            const int k = n0 - 1 + lpk;
            __fp16* d = &dec[lp * PSTRH];
            if (j >= 0 && j <= 510 && k >= 0 && k <= 510) {
                const float* base = imgb + (size_t)(2 * j) * IMG_W + 2 * k;
                // conv 2x2 stride-2, 2ch, ReLU (expression order = prior rounds, bit-exact argmax)
                float v0[4], v1[4];
                #pragma unroll
                for (int jj = 0; jj < 2; ++jj) {
                    #pragma unroll
                    for (int kk = 0; kk < 2; ++kk) {
                        const float2 ra = *(const float2*)(base + (size_t)(2 * jj) * IMG_W + 2 * kk);
                        const float2 rb = *(const float2*)(base + (size_t)(2 * jj + 1) * IMG_W + 2 * kk);
                        const float s0 = ra.x * wc[0][0] + ra.y * wc[0][1] + rb.x * wc[0][2] + rb.y * wc[0][3] + bc0;
                        const float s1 = ra.x * wc[1][0] + ra.y * wc[1][1] + rb.x * wc[1][2] + rb.y * wc[1][3] + bc1;
                        v0[jj * 2 + kk] = fmaxf(s0, 0.0f);
                        v1[jj * 2 + kk] = fmaxf(s1, 0.0f);
                    }
                }
                // first-occurrence argmax (jnp tie rule)
                int i0 = 0, i1 = 0;
                float mx0 = v0[0], mx1 = v1[0];
                #pragma unroll
                for (int q = 1; q < 4; ++q) {
                    if (v0[q] > mx0) { mx0 = v0[q]; i0 = q; }
                    if (v1[q] > mx1) { mx1 = v1[q]; i1 = q; }
                }
                const float z0 = fmaxf(mx0 * wb[0][0] + mx1 * wb[0][1] + bb0, 0.0f);
                const float z1 = fmaxf(mx0 * wb[1][0] + mx1 * wb[1][1] + bb1, 0.0f);

                // active quadrants: A = ch0-argmax quad, B = ch1-argmax quad (equal -> identical)
                const float ag1 = (i1 == i0) ? z1 : 0.0f;
                const float bg0 = (i0 == i1) ? z0 : 0.0f;
                float av[4], bv[4];
                #pragma unroll
                for (int q = 0; q < 4; ++q) {
                    av[q] = 1.0f / (1.0f + exp2f(z0 * nwd[0][q] + ag1 * nwd[1][q] + nbd));
                    bv[q] = 1.0f / (1.0f + exp2f(bg0 * nwd[0][q] + z1 * nwd[1][q] + nbd));
                }
                const h2 a01 = __builtin_amdgcn_cvt_pkrtz(av[0], av[1]);
                const h2 a23 = __builtin_amdgcn_cvt_pkrtz(av[2], av[3]);
                const h2 b01 = __builtin_amdgcn_cvt_pkrtz(bv[0], bv[1]);
                const h2 b23 = __builtin_amdgcn_cvt_pkrtz(bv[2], bv[3]);
                #pragma unroll
                for (int qd = 0; qd < 4; ++qd) {
                    const h2 q01 = (qd == i1) ? b01 : ((qd == i0) ? a01 : ch);
                    const h2 q23 = (qd == i1) ? b23 : ((qd == i0) ? a23 : ch);
                    float2 w; w.x = h2_as_f(q01); w.y = h2_as_f(q23);
                    *(float2*)(d + 4 * qd) = w;   // ds_write_b64
                }
            } else {
                float2 zw; zw.x = h2_as_f(zh); zw.y = h2_as_f(zh);
                #pragma unroll
                for (int qd = 0; qd < 4; ++qd) *(float2*)(d + 4 * qd) = zw;
            }
        }
    }
    __syncthreads();

    // ---- stage 2: gather 4 quadrants (packed f16 adds), normalize, store ----
    const int ty = t >> 4, tx = t & 15;
    const int m = m0 + ty, n = n0 + tx;
    h2 s01 = zh, s23 = zh;
    #pragma unroll
    for (int a = 0; a < 2; ++a) {        // a=0: patch j=m-1 (quad row 1); a=1: j=m (quad row 0)
        #pragma unroll
        for (int e = 0; e < 2; ++e) {    // e=0: patch k=n-1 (quad col 1); e=1: k=n (quad col 0)
            const int lp = (ty + a) * NPJ + (tx + e);
            const int qd = (1 - a) * 2 + (1 - e);
            const float2 w = *(const float2*)(dec + lp * PSTRH + 4 * qd);  // ds_read_b64
            s01 += f_as_h2(w.x);         // v_pk_add_f16
            s23 += f_as_h2(w.y);
        }
    }
    const float rcnt = 1.0f / (float)(((m >= 1) + (m <= 510)) * ((n >= 1) + (n <= 510)));
    float* outb = out + (size_t)b * IMG_H * IMG_W;
    *(float2*)(outb + (size_t)(2 * m) * IMG_W + 2 * n) =
        make_float2((float)s01.x * rcnt, (float)s01.y * rcnt);
    *(float2*)(outb + (size_t)(2 * m + 1) * IMG_W + 2 * n) =
        make_float2((float)s23.x * rcnt, (float)s23.y * rcnt);
}

extern "C" void kernel_launch(void* const* d_in, const int* in_sizes, int n_in,
                              void* d_out, int out_size, void* d_ws, size_t ws_size,
                              hipStream_t stream) {
    const float* img    = (const float*)d_in[0];
    const float* w_conv = (const float*)d_in[1];
    const float* b_conv = (const float*)d_in[2];
    const float* W_b    = (const float*)d_in[3];
    const float* b_b    = (const float*)d_in[4];
    const float* W_d    = (const float*)d_in[5];
    const float* b_d    = (const float*)d_in[6];
    float* out = (float*)d_out;

    dim3 block(256, 1, 1);
    dim3 grid(512 / TILES, 512 / TILES, 8);   // 32 x 32 x 8 blocks
    ae_fused<<<grid, block, 0, stream>>>(img, w_conv, b_conv, W_b, b_b, W_d, b_d, out);
}

// Round 7
// 108.058 us; speedup vs baseline: 1.0374x; 1.0374x over previous
//
#include <hip/hip_runtime.h>

#define IMG_H 1024
#define IMG_W 1024
#define TILES 15                 // 15x15 output tiles per block (30x30 px)
#define NPJ 16                   // 16x16 patches per block = 256 = blockDim
#define NPATCH (NPJ * NPJ)
#define PSTRH 20                 // __fp16 units per patch record (40 B: 16 used + pad)
#define NBLK 35                  // ceil(512/15)

typedef __attribute__((ext_vector_type(2))) __fp16 h2;

static __device__ __forceinline__ float h2_as_f(h2 v) {
    union { h2 h; float f; } u; u.h = v; return u.f;
}
static __device__ __forceinline__ h2 f_as_h2(float f) {
    union { float f; h2 h; } u; u.f = f; return u.h;
}

__global__ __launch_bounds__(256, 4) void ae_fused(
    const float* __restrict__ img,
    const float* __restrict__ w_conv,
    const float* __restrict__ b_conv,
    const float* __restrict__ W_b,
    const float* __restrict__ b_b,
    const float* __restrict__ W_d,
    const float* __restrict__ b_d,
    float* __restrict__ out)
{
    __shared__ __align__(16) __fp16 dec[NPATCH * PSTRH];   // 10240 B

    const int t  = threadIdx.x;
    const int ty = t >> 4, tx = t & 15;
    const int n0 = blockIdx.x * TILES;   // tile col base
    const int m0 = blockIdx.y * TILES;   // tile row base
    const int b  = blockIdx.z;

    // uniform weights; decoder weights pre-negated and pre-scaled by log2(e)
    const float LOG2E = 1.4426950408889634f;
    float wc[2][4], nwd[2][4], wb[2][2];
    #pragma unroll
    for (int c = 0; c < 2; ++c) {
        #pragma unroll
        for (int q = 0; q < 4; ++q) {
            wc[c][q]  = w_conv[c * 4 + q];
            nwd[c][q] = -W_d[c * 4 + q] * LOG2E;
        }
    }
    wb[0][0] = W_b[0]; wb[0][1] = W_b[1];
    wb[1][0] = W_b[2]; wb[1][1] = W_b[3];
    const float bc0 = b_conv[0], bc1 = b_conv[1];
    const float bb0 = b_b[0],   bb1 = b_b[1];
    const float nbd = -b_d[0] * LOG2E;
    const float scf = 1.0f / (1.0f + exp2f(nbd));            // sigmoid(b_d)
    const h2 ch = { (__fp16)scf, (__fp16)scf };
    const h2 zh = { (__fp16)0.0f, (__fp16)0.0f };

    const float* imgb = img + (size_t)b * IMG_H * IMG_W;

    // ---- stage 1: thread (ty,tx) owns patch (j,k) = (m0-1+ty, n0-1+tx) ----
    {
        const int j = m0 - 1 + ty;
        const int k = n0 - 1 + tx;
        __fp16* d = &dec[t * PSTRH];
        if (j >= 0 && j <= 510 && k >= 0 && k <= 510) {
            const int off = (j << 11) + (k << 1);   // 2j*1024 + 2k, 32-bit
            // conv 2x2 stride-2, 2ch, ReLU (same expression order as prior rounds)
            float v0[4], v1[4];
            #pragma unroll
            for (int jj = 0; jj < 2; ++jj) {
                #pragma unroll
                for (int kk = 0; kk < 2; ++kk) {
                    const float2 ra = *(const float2*)(imgb + off + (jj << 11) + (kk << 1));
                    const float2 rb = *(const float2*)(imgb + off + (jj << 11) + (kk << 1) + IMG_W);
                    const float s0 = ra.x * wc[0][0] + ra.y * wc[0][1] + rb.x * wc[0][2] + rb.y * wc[0][3] + bc0;
                    const float s1 = ra.x * wc[1][0] + ra.y * wc[1][1] + rb.x * wc[1][2] + rb.y * wc[1][3] + bc1;
                    v0[jj * 2 + kk] = fmaxf(s0, 0.0f);
                    v1[jj * 2 + kk] = fmaxf(s1, 0.0f);
                }
            }
            // first-occurrence argmax (jnp tie rule)
            int i0 = 0, i1 = 0;
            float mx0 = v0[0], mx1 = v1[0];
            #pragma unroll
            for (int q = 1; q < 4; ++q) {
                if (v0[q] > mx0) { mx0 = v0[q]; i0 = q; }
                if (v1[q] > mx1) { mx1 = v1[q]; i1 = q; }
            }
            const float z0 = fmaxf(mx0 * wb[0][0] + mx1 * wb[0][1] + bb0, 0.0f);
            const float z1 = fmaxf(mx0 * wb[1][0] + mx1 * wb[1][1] + bb1, 0.0f);

            // active quadrants: A = ch0-argmax quad, B = ch1-argmax quad
            const float ag1 = (i1 == i0) ? z1 : 0.0f;
            const float bg0 = (i0 == i1) ? z0 : 0.0f;
            float av[4], bv[4];
            #pragma unroll
            for (int q = 0; q < 4; ++q) {
                av[q] = 1.0f / (1.0f + exp2f(z0 * nwd[0][q] + ag1 * nwd[1][q] + nbd));
                bv[q] = 1.0f / (1.0f + exp2f(bg0 * nwd[0][q] + z1 * nwd[1][q] + nbd));
            }
            // fill all quads with the constant, then 2 indexed overwrites (B last = tie rule)
            float2 cw; cw.x = h2_as_f(ch); cw.y = h2_as_f(ch);
            #pragma unroll
            for (int qd = 0; qd < 4; ++qd) *(float2*)(d + 4 * qd) = cw;
            float2 aw; aw.x = h2_as_f(__builtin_amdgcn_cvt_pkrtz(av[0], av[1]));
                       aw.y = h2_as_f(__builtin_amdgcn_cvt_pkrtz(av[2], av[3]));
            *(float2*)(d + 4 * i0) = aw;
            float2 bw; bw.x = h2_as_f(__builtin_amdgcn_cvt_pkrtz(bv[0], bv[1]));
                       bw.y = h2_as_f(__builtin_amdgcn_cvt_pkrtz(bv[2], bv[3]));
            *(float2*)(d + 4 * i1) = bw;
        } else {
            float2 zw; zw.x = h2_as_f(zh); zw.y = h2_as_f(zh);
            #pragma unroll
            for (int qd = 0; qd < 4; ++qd) *(float2*)(d + 4 * qd) = zw;
        }
    }
    __syncthreads();

    // ---- stage 2: threads with ty,tx < 15 gather tile (m0+ty, n0+tx) ----
    if (ty < TILES && tx < TILES) {
        const int m = m0 + ty, n = n0 + tx;
        if (m < 512 && n < 512) {
            h2 s01 = zh, s23 = zh;
            #pragma unroll
            for (int a = 0; a < 2; ++a) {        // a=0: patch j=m-1 (quad row 1)
                #pragma unroll
                for (int e = 0; e < 2; ++e) {    // e=0: patch k=n-1 (quad col 1)
                    const int lp = ((ty + a) << 4) + (tx + e);
                    const int qd = (1 - a) * 2 + (1 - e);
                    const float2 w = *(const float2*)(dec + lp * PSTRH + 4 * qd);
                    s01 += f_as_h2(w.x);         // v_pk_add_f16
                    s23 += f_as_h2(w.y);
                }
            }
            const float rcnt = 1.0f / (float)(((m >= 1) + (m <= 510)) * ((n >= 1) + (n <= 510)));
            float* outb = out + (size_t)b * IMG_H * IMG_W;
            *(float2*)(outb + (size_t)(2 * m) * IMG_W + 2 * n) =
                make_float2((float)s01.x * rcnt, (float)s01.y * rcnt);
            *(float2*)(outb + (size_t)(2 * m + 1) * IMG_W + 2 * n) =
                make_float2((float)s23.x * rcnt, (float)s23.y * rcnt);
        }
    }
}

extern "C" void kernel_launch(void* const* d_in, const int* in_sizes, int n_in,
                              void* d_out, int out_size, void* d_ws, size_t ws_size,
                              hipStream_t stream) {
    const float* img    = (const float*)d_in[0];
    const float* w_conv = (const float*)d_in[1];
    const float* b_conv = (const float*)d_in[2];
    const float* W_b    = (const float*)d_in[3];
    const float* b_b    = (const float*)d_in[4];
    const float* W_d    = (const float*)d_in[5];
    const float* b_d    = (const float*)d_in[6];
    float* out = (float*)d_out;

    dim3 block(256, 1, 1);
    dim3 grid(NBLK, NBLK, 8);   // 35 x 35 x 8 blocks
    ae_fused<<<grid, block, 0, stream>>>(img, w_conv, b_conv, W_b, b_b, W_d, b_d, out);
}